// Round 12
// baseline (52.909 us; speedup 1.0000x reference)
//
#include <hip/hip_runtime.h>
#include <math.h>
#include <stdint.h>

#define N_FEAT 8192
#define DIM 512
#define KC 64
#define MF 128
#define TFT 32
#define NBLK 320       // >= max tiles (320); 256 work blocks + 64 prefetchers
#define NWORK 256
#define BKC 64         // d-chunk
#define NCH (DIM / BKC)
#define MAGIC1 0x13579BDF
#define MAGIC2 0x2468ACE1

typedef __attribute__((ext_vector_type(8))) _Float16 f16x8;
typedef __attribute__((ext_vector_type(4))) float f32x4;
typedef unsigned short ush;
typedef unsigned char uch;

__device__ __forceinline__ float wave_reduce_sum(float s) {
#pragma unroll
  for (int o = 32; o; o >>= 1) s += __shfl_xor(s, o);
  return s;
}

__device__ __forceinline__ int bsum4(unsigned w) {
  return (w & 0xff) + ((w >> 8) & 0xff) + ((w >> 16) & 0xff) + (w >> 24);
}

__device__ __forceinline__ uint4 cvt8(float4 a, float4 b, float& sq) {
  sq = fmaf(a.x, a.x, sq); sq = fmaf(a.y, a.y, sq);
  sq = fmaf(a.z, a.z, sq); sq = fmaf(a.w, a.w, sq);
  sq = fmaf(b.x, b.x, sq); sq = fmaf(b.y, b.y, sq);
  sq = fmaf(b.z, b.z, sq); sq = fmaf(b.w, b.w, sq);
  union { _Float16 h[8]; uint4 v; } o;
  o.h[0] = (_Float16)a.x; o.h[1] = (_Float16)a.y;
  o.h[2] = (_Float16)a.z; o.h[3] = (_Float16)a.w;
  o.h[4] = (_Float16)b.x; o.h[5] = (_Float16)b.y;
  o.h[6] = (_Float16)b.z; o.h[7] = (_Float16)b.w;
  return o.v;
}

__device__ __forceinline__ uint4 cvt8n(float4 a, float4 b) {
  union { _Float16 h[8]; uint4 v; } o;
  o.h[0] = (_Float16)a.x; o.h[1] = (_Float16)a.y;
  o.h[2] = (_Float16)a.z; o.h[3] = (_Float16)a.w;
  o.h[4] = (_Float16)b.x; o.h[5] = (_Float16)b.y;
  o.h[6] = (_Float16)b.z; o.h[7] = (_Float16)b.w;
  return o.v;
}

#define ALOAD(p) __hip_atomic_load((p), __ATOMIC_RELAXED, __HIP_MEMORY_SCOPE_AGENT)
#define ASTORE(p, v) __hip_atomic_store((p), (v), __ATOMIC_RELAXED, __HIP_MEMORY_SCOPE_AGENT)
#define AADD(p, v) __hip_atomic_fetch_add((p), (v), __ATOMIC_RELAXED, __HIP_MEMORY_SCOPE_AGENT)

struct SMemA {
  ush Ah[2][32 * 64];
  ush Bh[2][64 * 64];
  float c2s[64];
  float rv[32][2];
  int ri[32][2];
  int histL[64];
};
struct SMemB {
  int hpart[4][64];
  int hist[64];
  int meta[3];
  int wsum[4];
  int glist[TFT];
  ush Ab[2][32 * 64];
  ush Bb[2][128 * 64];
  float red[32][5];
  float f2s[32];
  float p2s[128];
};
union SMem { SMemA a; SMemB b; };

// Single fused kernel. Phase A (blocks 0..255): coarse assignment, 32 features
// x 64 clusters each, fp16 MFMA with 3-stage reg->LDS pipeline; writes only
// assign[8192] + histB[64x256 bytes] (48 KB dirty). Blocks 256..319: prefetch
// `fine` into L3. Low-contention device barrier (flag on its own cacheline,
// s_sleep(32) spin, self-resetting). Phase B (all 320): self-scheduled fine
// 32f x 128m MFMA tiles -> per-feature min -> mean.
__global__ void __launch_bounds__(256, 2) fused_kernel(
    const float* __restrict__ feat, const float* __restrict__ coarse,
    const float* __restrict__ fine, int* __restrict__ assign,
    uch* __restrict__ histB, int* __restrict__ bar, float* __restrict__ out) {
  __shared__ SMem sm;

  int t = threadIdx.x, bid = blockIdx.x;
  int l = t & 63, w = t >> 6;

  // ---- init gate: make barrier state {cnt,flag,done}=0 despite ws poison ----
  if (t == 0) {
    if (bid == 0) {
      bool ok = (ALOAD(bar + 96) == (int)MAGIC1) && (ALOAD(bar + 97) == (int)MAGIC2);
      if (!ok) {
        ASTORE(bar + 0, 0);   // counter
        ASTORE(bar + 32, 0);  // flag
        ASTORE(bar + 64, 0);  // done
        __threadfence();
        ASTORE(bar + 96, (int)MAGIC1);
        ASTORE(bar + 97, (int)MAGIC2);
      }
    } else {
      while (ALOAD(bar + 96) != (int)MAGIC1 || ALOAD(bar + 97) != (int)MAGIC2)
        __builtin_amdgcn_s_sleep(8);
    }
  }
  __syncthreads();

  // =================== PHASE A ===================
  if (bid < NWORK) {
    if (bid == 0 && t == 0) out[0] = 0.f;
    if (t < 64) sm.a.histL[t] = 0;

    int n0 = bid * 32;
    int slot = t & 7, r0 = t >> 3;
    int xs = (slot ^ (r0 & 7)) * 8;        // XOR 16B-slot swizzle
    const float* a0 = feat + (size_t)(n0 + r0) * DIM + slot * 8;
    const float* b0 = coarse + (size_t)r0 * DIM + slot * 8;
    const float* b1 = b0 + (size_t)32 * DIM;
    int offA = r0 * 64 + xs;
    int offB0 = r0 * 64 + xs, offB1 = (r0 + 32) * 64 + xs;

    int lc = l & 15, lk = l >> 4;
    int sx0 = (lk ^ (l & 7)) * 8;
    int fs = (w & 1) * 16;
    int cpair = w >> 1;
    int eA = (fs + lc) * 64;
    int eB0 = (cpair * 32 + lc) * 64, eB1 = (cpair * 32 + 16 + lc) * 64;

    float sb0 = 0.f, sb1 = 0.f;
    f32x4 acc0 = {0.f, 0.f, 0.f, 0.f}, acc1 = acc0;

    float4 pAa, pAb, pB0a, pB0b, pB1a, pB1b;
    float4 qAa, qAb, qB0a, qB0b, qB1a, qB1b;

#define K1LOAD(Aa, Ab_, B0a, B0b, B1a, B1b, c) {                        \
    int go = (c) * BKC;                                                 \
    Aa = *(const float4*)(a0 + go); Ab_ = *(const float4*)(a0 + go + 4);\
    B0a = *(const float4*)(b0 + go); B0b = *(const float4*)(b0 + go + 4);\
    B1a = *(const float4*)(b1 + go); B1b = *(const float4*)(b1 + go + 4); }
#define K1WRITE(Aa, Ab_, B0a, B0b, B1a, B1b, nb) {                      \
    *(uint4*)&sm.a.Ah[nb][offA] = cvt8n(Aa, Ab_);                       \
    *(uint4*)&sm.a.Bh[nb][offB0] = cvt8(B0a, B0b, sb0);                 \
    *(uint4*)&sm.a.Bh[nb][offB1] = cvt8(B1a, B1b, sb1); }
#define K1MM(cur) {                                                     \
    _Pragma("unroll")                                                   \
    for (int ksub = 0; ksub < 2; ksub++) {                              \
      int sx = sx0 ^ (ksub * 32);                                       \
      f16x8 av = *(const f16x8*)&sm.a.Ah[cur][eA + sx];                 \
      acc0 = __builtin_amdgcn_mfma_f32_16x16x32_f16(av, *(const f16x8*)&sm.a.Bh[cur][eB0 + sx], acc0, 0, 0, 0); \
      acc1 = __builtin_amdgcn_mfma_f32_16x16x32_f16(av, *(const f16x8*)&sm.a.Bh[cur][eB1 + sx], acc1, 0, 0, 0); \
    } }

    K1LOAD(pAa, pAb, pB0a, pB0b, pB1a, pB1b, 0);
    K1WRITE(pAa, pAb, pB0a, pB0b, pB1a, pB1b, 0);
    K1LOAD(qAa, qAb, qB0a, qB0b, qB1a, qB1b, 1);
    __syncthreads();

#pragma unroll
    for (int c = 0; c < NCH; c += 2) {
      if (c + 2 < NCH) K1LOAD(pAa, pAb, pB0a, pB0b, pB1a, pB1b, c + 2);
      K1MM(c & 1);
      if (c + 1 < NCH) K1WRITE(qAa, qAb, qB0a, qB0b, qB1a, qB1b, (c & 1) ^ 1);
      __syncthreads();
      if (c + 3 < NCH) K1LOAD(qAa, qAb, qB0a, qB0b, qB1a, qB1b, c + 3);
      K1MM((c + 1) & 1);
      if (c + 2 < NCH) K1WRITE(pAa, pAb, pB0a, pB0b, pB1a, pB1b, ((c + 1) & 1) ^ 1);
      __syncthreads();
    }

#pragma unroll
    for (int m = 1; m < 8; m <<= 1) {
      sb0 += __shfl_xor(sb0, m); sb1 += __shfl_xor(sb1, m);
    }
    if (slot == 0) { sm.a.c2s[r0] = sb0; sm.a.c2s[r0 + 32] = sb1; }
    __syncthreads();

    float c2v0 = sm.a.c2s[cpair * 32 + lc], c2v1 = sm.a.c2s[cpair * 32 + 16 + lc];
#pragma unroll
    for (int j = 0; j < 4; j++) {
      float bv = c2v0 - 2.f * acc0[j];
      int bi = cpair * 32 + lc;
      float v1 = c2v1 - 2.f * acc1[j];
      if (v1 < bv) { bv = v1; bi = cpair * 32 + 16 + lc; }
#pragma unroll
      for (int mask = 1; mask < 16; mask <<= 1) {
        float ov = __shfl_xor(bv, mask);
        int oi = __shfl_xor(bi, mask);
        if (ov < bv || (ov == bv && oi < bi)) { bv = ov; bi = oi; }
      }
      if (lc == 0) {
        sm.a.rv[fs + lk * 4 + j][cpair] = bv;
        sm.a.ri[fs + lk * 4 + j][cpair] = bi;
      }
    }
    __syncthreads();
    if (t < 32) {
      float v0 = sm.a.rv[t][0], v1 = sm.a.rv[t][1];
      int bi = (v1 < v0) ? sm.a.ri[t][1] : sm.a.ri[t][0];  // ties -> lower idx
      assign[n0 + t] = bi;
      atomicAdd(&sm.a.histL[bi], 1);
    }
    __syncthreads();
    if (t < 64) histB[(size_t)t * NWORK + bid] = (uch)sm.a.histL[t];
  } else {
    // ---- prefetch `fine` into L3 for phase B (64 blocks x 256 KB) ----
    const float4* src = (const float4*)(fine) + (size_t)(bid - NWORK) * 16384 + t;
    float s = 0.f;
#pragma unroll 8
    for (int i = 0; i < 64; i++) {
      float4 v = src[i * 256];
      s += v.x + v.y + v.z + v.w;
    }
    asm volatile("" : : "v"(s));   // keep loads live (rule #17)
  }

  // =================== DEVICE BARRIER (low-contention) ===================
  if (t == 0) {
    __threadfence();                                   // release phase-A writes
    if (bid < NWORK) {
      int old = AADD(bar + 0, 1);
      if (old == NWORK - 1) ASTORE(bar + 32, 1);       // last arriver sets flag
    }
    while (ALOAD(bar + 32) == 0) __builtin_amdgcn_s_sleep(32);
    int d = AADD(bar + 64, 1);                         // leave
    if (d == NBLK - 1) {                               // all exited the wait
      ASTORE(bar + 0, 0); ASTORE(bar + 32, 0); ASTORE(bar + 64, 0);
    }
    __threadfence();                                   // acquire
  }
  __syncthreads();

  // =================== PHASE B: fine tiles ===================
  {
    int ksl = t & 63, q = t >> 6;
    const uint4* hp = (const uint4*)(histB + (size_t)ksl * NWORK + q * 64);
    uint4 h0 = hp[0], h1 = hp[1], h2 = hp[2], h3 = hp[3];
    int ps = bsum4(h0.x) + bsum4(h0.y) + bsum4(h0.z) + bsum4(h0.w) +
             bsum4(h1.x) + bsum4(h1.y) + bsum4(h1.z) + bsum4(h1.w) +
             bsum4(h2.x) + bsum4(h2.y) + bsum4(h2.z) + bsum4(h2.w) +
             bsum4(h3.x) + bsum4(h3.y) + bsum4(h3.z) + bsum4(h3.w);
    sm.b.hpart[q][ksl] = ps;
  }
  __syncthreads();
  if (t < 64) {
    int c = sm.b.hpart[0][t] + sm.b.hpart[1][t] + sm.b.hpart[2][t] + sm.b.hpart[3][t];
    sm.b.hist[t] = c;
    int nt = (c + TFT - 1) / TFT;
    int s2 = nt;
#pragma unroll
    for (int o = 1; o < 64; o <<= 1) {
      int v = __shfl_up(s2, o);
      if (t >= o) s2 += v;
    }
    int tb = s2 - nt;
    if (t == 63) sm.b.meta[2] = s2;
    if (bid >= tb && bid < tb + nt) { sm.b.meta[0] = t; sm.b.meta[1] = bid - tb; }
  }
  __syncthreads();
  if (bid >= sm.b.meta[2]) return;
  int k = sm.b.meta[0], tile = sm.b.meta[1];
  int nk = sm.b.hist[k];
  int f0 = tile * TFT;
  int nf = min(TFT, nk - f0);

  int cntk = 0;
#pragma unroll
  for (int j = 0; j < 32; j++) cntk += (assign[t + j * 256] == k) ? 1 : 0;
  int inc = cntk;
#pragma unroll
  for (int o = 1; o < 64; o <<= 1) {
    int v = __shfl_up(inc, o);
    if (l >= o) inc += v;
  }
  if (l == 63) sm.b.wsum[w] = inc;
  __syncthreads();
  int rank = inc - cntk;
#pragma unroll
  for (int w2 = 0; w2 < 4; w2++) rank += (w2 < w) ? sm.b.wsum[w2] : 0;
#pragma unroll
  for (int j = 0; j < 32; j++) {
    int i = t + j * 256;
    if (assign[i] == k) {
      int rr = rank - f0;
      if (rr >= 0 && rr < TFT) sm.b.glist[rr] = i;
      rank++;
    }
  }
  __syncthreads();

  int sl8 = l >> 3, sl7 = l & 7;
  int slotw = sl7 ^ sl8;

  int arow = w * 8 + sl8;
  int agidx = sm.b.glist[min(arow, nf - 1)];
  const float* asrc = feat + (size_t)agidx * DIM + sl7 * 8;
  int aoff = arow * 64 + slotw * 8;
  int brow0 = w * 32 + 0 * 8 + sl8;
  int brow1 = w * 32 + 1 * 8 + sl8;
  int brow2 = w * 32 + 2 * 8 + sl8;
  int brow3 = w * 32 + 3 * 8 + sl8;
  const float* bsrc0 = fine + ((size_t)k * MF + brow0) * DIM + sl7 * 8;
  const float* bsrc1 = fine + ((size_t)k * MF + brow1) * DIM + sl7 * 8;
  const float* bsrc2 = fine + ((size_t)k * MF + brow2) * DIM + sl7 * 8;
  const float* bsrc3 = fine + ((size_t)k * MF + brow3) * DIM + sl7 * 8;
  int boff0 = brow0 * 64 + slotw * 8;
  int boff1 = brow1 * 64 + slotw * 8;
  int boff2 = brow2 * 64 + slotw * 8;
  int boff3 = brow3 * 64 + slotw * 8;

  int lc = l & 15, lk = l >> 4;
  int sx0 = (lk ^ sl7) * 8;
  int eA0 = lc * 64, eA1 = (16 + lc) * 64;
  int eB0 = (w * 32 + lc) * 64, eB1 = (w * 32 + 16 + lc) * 64;

  float sqA = 0.f, sqB0 = 0.f, sqB1 = 0.f, sqB2 = 0.f, sqB3 = 0.f;
  f32x4 acc00 = {0.f, 0.f, 0.f, 0.f}, acc01 = acc00, acc10 = acc00, acc11 = acc00;

  float4 pAa, pAb, pB0a, pB0b, pB1a, pB1b, pB2a, pB2b, pB3a, pB3b;
  float4 qAa, qAb, qB0a, qB0b, qB1a, qB1b, qB2a, qB2b, qB3a, qB3b;

#define K2LOAD(Aa, Ab_, B0a, B0b, B1a, B1b, B2a, B2b, B3a, B3b, c) {     \
    int go = (c) * BKC;                                                  \
    Aa = *(const float4*)(asrc + go); Ab_ = *(const float4*)(asrc + go + 4); \
    B0a = *(const float4*)(bsrc0 + go); B0b = *(const float4*)(bsrc0 + go + 4); \
    B1a = *(const float4*)(bsrc1 + go); B1b = *(const float4*)(bsrc1 + go + 4); \
    B2a = *(const float4*)(bsrc2 + go); B2b = *(const float4*)(bsrc2 + go + 4); \
    B3a = *(const float4*)(bsrc3 + go); B3b = *(const float4*)(bsrc3 + go + 4); }
#define K2WRITE(Aa, Ab_, B0a, B0b, B1a, B1b, B2a, B2b, B3a, B3b, nb) {   \
    *(uint4*)&sm.b.Ab[nb][aoff] = cvt8(Aa, Ab_, sqA);                    \
    *(uint4*)&sm.b.Bb[nb][boff0] = cvt8(B0a, B0b, sqB0);                 \
    *(uint4*)&sm.b.Bb[nb][boff1] = cvt8(B1a, B1b, sqB1);                 \
    *(uint4*)&sm.b.Bb[nb][boff2] = cvt8(B2a, B2b, sqB2);                 \
    *(uint4*)&sm.b.Bb[nb][boff3] = cvt8(B3a, B3b, sqB3); }
#define K2MM(cur) {                                                      \
    _Pragma("unroll")                                                    \
    for (int ksub = 0; ksub < 2; ksub++) {                               \
      int sx = sx0 ^ (ksub * 32);                                        \
      f16x8 a0 = *(const f16x8*)&sm.b.Ab[cur][eA0 + sx];                 \
      f16x8 a1 = *(const f16x8*)&sm.b.Ab[cur][eA1 + sx];                 \
      f16x8 b0 = *(const f16x8*)&sm.b.Bb[cur][eB0 + sx];                 \
      f16x8 b1 = *(const f16x8*)&sm.b.Bb[cur][eB1 + sx];                 \
      acc00 = __builtin_amdgcn_mfma_f32_16x16x32_f16(a0, b0, acc00, 0, 0, 0); \
      acc01 = __builtin_amdgcn_mfma_f32_16x16x32_f16(a0, b1, acc01, 0, 0, 0); \
      acc10 = __builtin_amdgcn_mfma_f32_16x16x32_f16(a1, b0, acc10, 0, 0, 0); \
      acc11 = __builtin_amdgcn_mfma_f32_16x16x32_f16(a1, b1, acc11, 0, 0, 0); \
    } }

  K2LOAD(pAa, pAb, pB0a, pB0b, pB1a, pB1b, pB2a, pB2b, pB3a, pB3b, 0);
  K2WRITE(pAa, pAb, pB0a, pB0b, pB1a, pB1b, pB2a, pB2b, pB3a, pB3b, 0);
  K2LOAD(qAa, qAb, qB0a, qB0b, qB1a, qB1b, qB2a, qB2b, qB3a, qB3b, 1);
  __syncthreads();

#pragma unroll
  for (int c = 0; c < NCH; c += 2) {
    if (c + 2 < NCH) K2LOAD(pAa, pAb, pB0a, pB0b, pB1a, pB1b, pB2a, pB2b, pB3a, pB3b, c + 2);
    K2MM(c & 1);
    if (c + 1 < NCH) K2WRITE(qAa, qAb, qB0a, qB0b, qB1a, qB1b, qB2a, qB2b, qB3a, qB3b, (c & 1) ^ 1);
    __syncthreads();
    if (c + 3 < NCH) K2LOAD(qAa, qAb, qB0a, qB0b, qB1a, qB1b, qB2a, qB2b, qB3a, qB3b, c + 3);
    K2MM((c + 1) & 1);
    if (c + 2 < NCH) K2WRITE(pAa, pAb, pB0a, pB0b, pB1a, pB1b, pB2a, pB2b, pB3a, pB3b, ((c + 1) & 1) ^ 1);
    __syncthreads();
  }

#pragma unroll
  for (int m = 1; m < 8; m <<= 1) {
    sqA += __shfl_xor(sqA, m);
    sqB0 += __shfl_xor(sqB0, m); sqB1 += __shfl_xor(sqB1, m);
    sqB2 += __shfl_xor(sqB2, m); sqB3 += __shfl_xor(sqB3, m);
  }
  if (sl7 == 0) {
    sm.b.f2s[arow] = sqA;
    sm.b.p2s[brow0] = sqB0; sm.b.p2s[brow1] = sqB1;
    sm.b.p2s[brow2] = sqB2; sm.b.p2s[brow3] = sqB3;
  }
  __syncthreads();

  float p2v0 = sm.b.p2s[w * 32 + lc], p2v1 = sm.b.p2s[w * 32 + 16 + lc];
  float v0[4], v1[4];
#pragma unroll
  for (int j = 0; j < 4; j++) {
    v0[j] = fminf(p2v0 - 2.f * acc00[j], p2v1 - 2.f * acc01[j]);
    v1[j] = fminf(p2v0 - 2.f * acc10[j], p2v1 - 2.f * acc11[j]);
  }
#pragma unroll
  for (int mask = 1; mask < 16; mask <<= 1) {
#pragma unroll
    for (int j = 0; j < 4; j++) {
      v0[j] = fminf(v0[j], __shfl_xor(v0[j], mask));
      v1[j] = fminf(v1[j], __shfl_xor(v1[j], mask));
    }
  }
  if (lc == 0) {
#pragma unroll
    for (int j = 0; j < 4; j++) {
      sm.b.red[lk * 4 + j][w] = v0[j];
      sm.b.red[16 + lk * 4 + j][w] = v1[j];
    }
  }
  __syncthreads();
  if (t < 64) {
    float val = 0.f;
    if (t < nf) {
      float m = fminf(fminf(sm.b.red[t][0], sm.b.red[t][1]),
                      fminf(sm.b.red[t][2], sm.b.red[t][3]));
      float d2 = sm.b.f2s[t] + m;
      val = sqrtf(fmaxf(d2, 0.f)) * (1.0f / (float)N_FEAT);
    }
    val = wave_reduce_sum(val);
    if (t == 0) atomicAdd(out, val);
  }
}

extern "C" void kernel_launch(void* const* d_in, const int* in_sizes, int n_in,
                              void* d_out, int out_size, void* d_ws, size_t ws_size,
                              hipStream_t stream) {
  (void)in_sizes; (void)n_in; (void)out_size; (void)ws_size;
  const float* feat   = (const float*)d_in[0];
  const float* coarse = (const float*)d_in[1];
  const float* fine   = (const float*)d_in[2];
  float* out = (float*)d_out;

  int* assign = (int*)d_ws;                        // 8192 ints
  uch* histB  = (uch*)(assign + N_FEAT);           // 64 * 256 bytes, transposed
  int* bar    = (int*)(histB + KC * NWORK);        // 128 ints (3 cachelines + magics)

  fused_kernel<<<NBLK, 256, 0, stream>>>(feat, coarse, fine, assign, histB, bar, out);
}

// Round 13
// 31.114 us; speedup vs baseline: 1.7005x; 1.7005x over previous
//
#include <hip/hip_runtime.h>
#include <math.h>
#include <stdint.h>

#define N_FEAT 8192
#define DIM 512
#define KC 64
#define MF 128
#define TFT 32
#define MAXT2 320      // sum ceil(nk/32) <= 8192/32 + 64
#define BKC 64         // d-chunk
#define NCH (DIM / BKC)
#define K1BLK 256      // 32 features each

typedef __attribute__((ext_vector_type(8))) _Float16 f16x8;
typedef __attribute__((ext_vector_type(4))) float f32x4;
typedef unsigned short ush;
typedef unsigned char uch;

__device__ __forceinline__ float wave_reduce_sum(float s) {
#pragma unroll
  for (int o = 32; o; o >>= 1) s += __shfl_xor(s, o);
  return s;
}

__device__ __forceinline__ int bsum4(unsigned w) {
  return (w & 0xff) + ((w >> 8) & 0xff) + ((w >> 16) & 0xff) + (w >> 24);
}

// convert 8 f32 -> 8 fp16 packed in uint4; accumulate exact f32 sq-sum
__device__ __forceinline__ uint4 cvt8(float4 a, float4 b, float& sq) {
  sq = fmaf(a.x, a.x, sq); sq = fmaf(a.y, a.y, sq);
  sq = fmaf(a.z, a.z, sq); sq = fmaf(a.w, a.w, sq);
  sq = fmaf(b.x, b.x, sq); sq = fmaf(b.y, b.y, sq);
  sq = fmaf(b.z, b.z, sq); sq = fmaf(b.w, b.w, sq);
  union { _Float16 h[8]; uint4 v; } o;
  o.h[0] = (_Float16)a.x; o.h[1] = (_Float16)a.y;
  o.h[2] = (_Float16)a.z; o.h[3] = (_Float16)a.w;
  o.h[4] = (_Float16)b.x; o.h[5] = (_Float16)b.y;
  o.h[6] = (_Float16)b.z; o.h[7] = (_Float16)b.w;
  return o.v;
}

__device__ __forceinline__ uint4 cvt8n(float4 a, float4 b) {
  union { _Float16 h[8]; uint4 v; } o;
  o.h[0] = (_Float16)a.x; o.h[1] = (_Float16)a.y;
  o.h[2] = (_Float16)a.z; o.h[3] = (_Float16)a.w;
  o.h[4] = (_Float16)b.x; o.h[5] = (_Float16)b.y;
  o.h[6] = (_Float16)b.z; o.h[7] = (_Float16)b.w;
  return o.v;
}

// K1: coarse assignment. 256 blocks x 32 features x all 64 clusters.
// 3-stage pipeline: two register staging sets (P,Q), chunk i lives in set i&1.
__global__ void __launch_bounds__(256) k1_assign_kernel(
    const float* __restrict__ feat, const float* __restrict__ coarse,
    int* __restrict__ assign, uch* __restrict__ histB,
    float* __restrict__ out) {
  __shared__ ush Ah[2][32 * 64];
  __shared__ ush Bh[2][64 * 64];
  __shared__ float c2s[64];
  __shared__ float rv[32][2];
  __shared__ int ri[32][2];
  __shared__ int histL[64];

  int t = threadIdx.x, bid = blockIdx.x;
  int l = t & 63, w = t >> 6;
  if (bid == 0 && t == 0) out[0] = 0.f;
  if (t < 64) histL[t] = 0;

  int n0 = bid * 32;
  int slot = t & 7, r0 = t >> 3;
  int xs = (slot ^ (r0 & 7)) * 8;          // XOR 16B-slot swizzle
  const float* a0 = feat + (size_t)(n0 + r0) * DIM + slot * 8;
  const float* b0 = coarse + (size_t)r0 * DIM + slot * 8;
  const float* b1 = b0 + (size_t)32 * DIM;
  int offA = r0 * 64 + xs;
  int offB0 = r0 * 64 + xs, offB1 = (r0 + 32) * 64 + xs;

  int lc = l & 15, lk = l >> 4;
  int sx0 = (lk ^ (l & 7)) * 8;
  int fs = (w & 1) * 16;
  int cpair = w >> 1;
  int eA = (fs + lc) * 64;
  int eB0 = (cpair * 32 + lc) * 64, eB1 = (cpair * 32 + 16 + lc) * 64;

  float sb0 = 0.f, sb1 = 0.f;
  f32x4 acc0 = {0.f, 0.f, 0.f, 0.f}, acc1 = acc0;

  float4 pAa, pAb, pB0a, pB0b, pB1a, pB1b;
  float4 qAa, qAb, qB0a, qB0b, qB1a, qB1b;

#define K1LOAD(Aa, Ab_, B0a, B0b, B1a, B1b, c) {                        \
    int go = (c) * BKC;                                                 \
    Aa = *(const float4*)(a0 + go); Ab_ = *(const float4*)(a0 + go + 4);\
    B0a = *(const float4*)(b0 + go); B0b = *(const float4*)(b0 + go + 4);\
    B1a = *(const float4*)(b1 + go); B1b = *(const float4*)(b1 + go + 4); }
#define K1WRITE(Aa, Ab_, B0a, B0b, B1a, B1b, nb) {                      \
    *(uint4*)&Ah[nb][offA] = cvt8n(Aa, Ab_);                            \
    *(uint4*)&Bh[nb][offB0] = cvt8(B0a, B0b, sb0);                      \
    *(uint4*)&Bh[nb][offB1] = cvt8(B1a, B1b, sb1); }
#define K1MM(cur) {                                                     \
    _Pragma("unroll")                                                   \
    for (int ksub = 0; ksub < 2; ksub++) {                              \
      int sx = sx0 ^ (ksub * 32);                                       \
      f16x8 av = *(const f16x8*)&Ah[cur][eA + sx];                      \
      acc0 = __builtin_amdgcn_mfma_f32_16x16x32_f16(av, *(const f16x8*)&Bh[cur][eB0 + sx], acc0, 0, 0, 0); \
      acc1 = __builtin_amdgcn_mfma_f32_16x16x32_f16(av, *(const f16x8*)&Bh[cur][eB1 + sx], acc1, 0, 0, 0); \
    } }

  // prolog: chunk0 -> P -> LDS0 ; chunk1 -> Q (in flight)
  K1LOAD(pAa, pAb, pB0a, pB0b, pB1a, pB1b, 0);
  K1WRITE(pAa, pAb, pB0a, pB0b, pB1a, pB1b, 0);
  K1LOAD(qAa, qAb, qB0a, qB0b, qB1a, qB1b, 1);
  __syncthreads();

#pragma unroll
  for (int c = 0; c < NCH; c += 2) {
    // even iter: free set = P (chunk c in LDS), held = Q (chunk c+1)
    if (c + 2 < NCH) K1LOAD(pAa, pAb, pB0a, pB0b, pB1a, pB1b, c + 2);
    K1MM(c & 1);
    if (c + 1 < NCH) K1WRITE(qAa, qAb, qB0a, qB0b, qB1a, qB1b, (c & 1) ^ 1);
    __syncthreads();
    // odd iter c+1: free set = Q, held = P (chunk c+2)
    if (c + 3 < NCH) K1LOAD(qAa, qAb, qB0a, qB0b, qB1a, qB1b, c + 3);
    K1MM((c + 1) & 1);
    if (c + 2 < NCH) K1WRITE(pAa, pAb, pB0a, pB0b, pB1a, pB1b, ((c + 1) & 1) ^ 1);
    __syncthreads();
  }

  // exact c2 norms: reduce across the 8 slot-lanes of each staging row
#pragma unroll
  for (int m = 1; m < 8; m <<= 1) {
    sb0 += __shfl_xor(sb0, m); sb1 += __shfl_xor(sb1, m);
  }
  if (slot == 0) { c2s[r0] = sb0; c2s[r0 + 32] = sb1; }
  __syncthreads();

  float c2v0 = c2s[cpair * 32 + lc], c2v1 = c2s[cpair * 32 + 16 + lc];
#pragma unroll
  for (int j = 0; j < 4; j++) {
    float bv = c2v0 - 2.f * acc0[j];
    int bi = cpair * 32 + lc;
    float v1 = c2v1 - 2.f * acc1[j];
    if (v1 < bv) { bv = v1; bi = cpair * 32 + 16 + lc; }
#pragma unroll
    for (int mask = 1; mask < 16; mask <<= 1) {
      float ov = __shfl_xor(bv, mask);
      int oi = __shfl_xor(bi, mask);
      if (ov < bv || (ov == bv && oi < bi)) { bv = ov; bi = oi; }
    }
    if (lc == 0) {
      rv[fs + lk * 4 + j][cpair] = bv;
      ri[fs + lk * 4 + j][cpair] = bi;
    }
  }
  __syncthreads();
  if (t < 32) {
    float v0 = rv[t][0], v1 = rv[t][1];
    int bi = (v1 < v0) ? ri[t][1] : ri[t][0];   // ties -> half0 (lower index)
    assign[n0 + t] = bi;
    atomicAdd(&histL[bi], 1);
  }
  __syncthreads();
  if (t < 64) histB[(size_t)t * K1BLK + bid] = (uch)histL[t];
}

// K2: fine distances via fp16 MFMA, self-scheduled, 32f x 128m per tile,
// 3-stage staging pipeline. B chunk-0/1 loads issued BEFORE the rank-scan
// (B depends only on k) so their cold-miss latency hides under the scan.
__global__ void __launch_bounds__(256) fine_mfma_kernel(
    const float* __restrict__ feat, const float* __restrict__ fine,
    const int* __restrict__ assign, const uch* __restrict__ histB,
    float* __restrict__ out) {
  __shared__ int hpart[4][64];
  __shared__ int hist[64];
  __shared__ int meta[3];
  __shared__ int wsum[4];
  __shared__ int glist[TFT];
  __shared__ ush Ab[2][32 * 64];
  __shared__ ush Bb[2][128 * 64];
  __shared__ float red[32][5];
  __shared__ float f2s[32];
  __shared__ float p2s[128];

  int t = threadIdx.x, bid = blockIdx.x;
  int l = t & 63, w = t >> 6;

  // histogram: coalesced uint4 loads over transposed bytes
  {
    int ksl = t & 63, q = t >> 6;
    const uint4* hp = (const uint4*)(histB + (size_t)ksl * K1BLK + q * 64);
    uint4 h0 = hp[0], h1 = hp[1], h2 = hp[2], h3 = hp[3];
    int ps = bsum4(h0.x) + bsum4(h0.y) + bsum4(h0.z) + bsum4(h0.w) +
             bsum4(h1.x) + bsum4(h1.y) + bsum4(h1.z) + bsum4(h1.w) +
             bsum4(h2.x) + bsum4(h2.y) + bsum4(h2.z) + bsum4(h2.w) +
             bsum4(h3.x) + bsum4(h3.y) + bsum4(h3.z) + bsum4(h3.w);
    hpart[q][ksl] = ps;
  }
  __syncthreads();
  if (t < 64) {
    int c = hpart[0][t] + hpart[1][t] + hpart[2][t] + hpart[3][t];
    hist[t] = c;
    int nt = (c + TFT - 1) / TFT;
    int s2 = nt;
#pragma unroll
    for (int o = 1; o < 64; o <<= 1) {
      int v = __shfl_up(s2, o);
      if (t >= o) s2 += v;
    }
    int tb = s2 - nt;
    if (t == 63) meta[2] = s2;
    if (bid >= tb && bid < tb + nt) { meta[0] = t; meta[1] = bid - tb; }
  }
  __syncthreads();
  if (bid >= meta[2]) return;
  int k = meta[0], tile = meta[1];
  int nk = hist[k];
  int f0 = tile * TFT;
  int nf = min(TFT, nk - f0);

  int sl8 = l >> 3, sl7 = l & 7;
  int slotw = sl7 ^ sl8;

  // ---- B addresses depend only on k: issue chunk-0/1 B loads NOW ----
  int brow0 = w * 32 + 0 * 8 + sl8;
  int brow1 = w * 32 + 1 * 8 + sl8;
  int brow2 = w * 32 + 2 * 8 + sl8;
  int brow3 = w * 32 + 3 * 8 + sl8;
  const float* bsrc0 = fine + ((size_t)k * MF + brow0) * DIM + sl7 * 8;
  const float* bsrc1 = fine + ((size_t)k * MF + brow1) * DIM + sl7 * 8;
  const float* bsrc2 = fine + ((size_t)k * MF + brow2) * DIM + sl7 * 8;
  const float* bsrc3 = fine + ((size_t)k * MF + brow3) * DIM + sl7 * 8;

  float4 pAa, pAb, pB0a, pB0b, pB1a, pB1b, pB2a, pB2b, pB3a, pB3b;
  float4 qAa, qAb, qB0a, qB0b, qB1a, qB1b, qB2a, qB2b, qB3a, qB3b;

#define K2LOADB(B0a, B0b, B1a, B1b, B2a, B2b, B3a, B3b, c) {             \
    int go = (c) * BKC;                                                  \
    B0a = *(const float4*)(bsrc0 + go); B0b = *(const float4*)(bsrc0 + go + 4); \
    B1a = *(const float4*)(bsrc1 + go); B1b = *(const float4*)(bsrc1 + go + 4); \
    B2a = *(const float4*)(bsrc2 + go); B2b = *(const float4*)(bsrc2 + go + 4); \
    B3a = *(const float4*)(bsrc3 + go); B3b = *(const float4*)(bsrc3 + go + 4); }
#define K2LOADA(Aa, Ab_, c) {                                            \
    int go = (c) * BKC;                                                  \
    Aa = *(const float4*)(asrc + go); Ab_ = *(const float4*)(asrc + go + 4); }

  K2LOADB(pB0a, pB0b, pB1a, pB1b, pB2a, pB2b, pB3a, pB3b, 0);
  K2LOADB(qB0a, qB0b, qB1a, qB1b, qB2a, qB2b, qB3a, qB3b, 1);

  // ---- rank-scan (B loads in flight underneath) ----
  int cntk = 0;
#pragma unroll
  for (int j = 0; j < 32; j++) cntk += (assign[t + j * 256] == k) ? 1 : 0;
  int inc = cntk;
#pragma unroll
  for (int o = 1; o < 64; o <<= 1) {
    int v = __shfl_up(inc, o);
    if (l >= o) inc += v;
  }
  if (l == 63) wsum[w] = inc;
  __syncthreads();
  int rank = inc - cntk;
#pragma unroll
  for (int w2 = 0; w2 < 4; w2++) rank += (w2 < w) ? wsum[w2] : 0;
#pragma unroll
  for (int j = 0; j < 32; j++) {
    int i = t + j * 256;
    if (assign[i] == k) {
      int rr = rank - f0;
      if (rr >= 0 && rr < TFT) glist[rr] = i;
      rank++;
    }
  }
  __syncthreads();

  int arow = w * 8 + sl8;
  int agidx = glist[min(arow, nf - 1)];
  const float* asrc = feat + (size_t)agidx * DIM + sl7 * 8;
  int aoff = arow * 64 + slotw * 8;
  int boff0 = brow0 * 64 + slotw * 8;
  int boff1 = brow1 * 64 + slotw * 8;
  int boff2 = brow2 * 64 + slotw * 8;
  int boff3 = brow3 * 64 + slotw * 8;

  int lc = l & 15, lk = l >> 4;
  int sx0 = (lk ^ sl7) * 8;
  int eA0 = lc * 64, eA1 = (16 + lc) * 64;
  int eB0 = (w * 32 + lc) * 64, eB1 = (w * 32 + 16 + lc) * 64;

  float sqA = 0.f, sqB0 = 0.f, sqB1 = 0.f, sqB2 = 0.f, sqB3 = 0.f;
  f32x4 acc00 = {0.f, 0.f, 0.f, 0.f}, acc01 = acc00, acc10 = acc00, acc11 = acc00;

#define K2WRITE(Aa, Ab_, B0a, B0b, B1a, B1b, B2a, B2b, B3a, B3b, nb) {   \
    *(uint4*)&Ab[nb][aoff] = cvt8(Aa, Ab_, sqA);                         \
    *(uint4*)&Bb[nb][boff0] = cvt8(B0a, B0b, sqB0);                      \
    *(uint4*)&Bb[nb][boff1] = cvt8(B1a, B1b, sqB1);                      \
    *(uint4*)&Bb[nb][boff2] = cvt8(B2a, B2b, sqB2);                      \
    *(uint4*)&Bb[nb][boff3] = cvt8(B3a, B3b, sqB3); }
#define K2MM(cur) {                                                      \
    _Pragma("unroll")                                                    \
    for (int ksub = 0; ksub < 2; ksub++) {                               \
      int sx = sx0 ^ (ksub * 32);                                        \
      f16x8 a0 = *(const f16x8*)&Ab[cur][eA0 + sx];                      \
      f16x8 a1 = *(const f16x8*)&Ab[cur][eA1 + sx];                      \
      f16x8 b0 = *(const f16x8*)&Bb[cur][eB0 + sx];                      \
      f16x8 b1 = *(const f16x8*)&Bb[cur][eB1 + sx];                      \
      acc00 = __builtin_amdgcn_mfma_f32_16x16x32_f16(a0, b0, acc00, 0, 0, 0); \
      acc01 = __builtin_amdgcn_mfma_f32_16x16x32_f16(a0, b1, acc01, 0, 0, 0); \
      acc10 = __builtin_amdgcn_mfma_f32_16x16x32_f16(a1, b0, acc10, 0, 0, 0); \
      acc11 = __builtin_amdgcn_mfma_f32_16x16x32_f16(a1, b1, acc11, 0, 0, 0); \
    } }

  // prolog: A chunk0/1 loads; write chunk0 (P) to LDS0; chunk1 (Q) held
  K2LOADA(pAa, pAb, 0);
  K2LOADA(qAa, qAb, 1);
  K2WRITE(pAa, pAb, pB0a, pB0b, pB1a, pB1b, pB2a, pB2b, pB3a, pB3b, 0);
  __syncthreads();

#pragma unroll
  for (int c = 0; c < NCH; c += 2) {
    if (c + 2 < NCH) {
      K2LOADA(pAa, pAb, c + 2);
      K2LOADB(pB0a, pB0b, pB1a, pB1b, pB2a, pB2b, pB3a, pB3b, c + 2);
    }
    K2MM(c & 1);
    if (c + 1 < NCH) K2WRITE(qAa, qAb, qB0a, qB0b, qB1a, qB1b, qB2a, qB2b, qB3a, qB3b, (c & 1) ^ 1);
    __syncthreads();
    if (c + 3 < NCH) {
      K2LOADA(qAa, qAb, c + 3);
      K2LOADB(qB0a, qB0b, qB1a, qB1b, qB2a, qB2b, qB3a, qB3b, c + 3);
    }
    K2MM((c + 1) & 1);
    if (c + 2 < NCH) K2WRITE(pAa, pAb, pB0a, pB0b, pB1a, pB1b, pB2a, pB2b, pB3a, pB3b, ((c + 1) & 1) ^ 1);
    __syncthreads();
  }

  // exact f2/p2 row norms: reduce across the 8 slot-lanes of each staging row
#pragma unroll
  for (int m = 1; m < 8; m <<= 1) {
    sqA += __shfl_xor(sqA, m);
    sqB0 += __shfl_xor(sqB0, m); sqB1 += __shfl_xor(sqB1, m);
    sqB2 += __shfl_xor(sqB2, m); sqB3 += __shfl_xor(sqB3, m);
  }
  if (sl7 == 0) {
    f2s[arow] = sqA;
    p2s[brow0] = sqB0; p2s[brow1] = sqB1;
    p2s[brow2] = sqB2; p2s[brow3] = sqB3;
  }
  __syncthreads();

  float p2v0 = p2s[w * 32 + lc], p2v1 = p2s[w * 32 + 16 + lc];
  float v0[4], v1[4];
#pragma unroll
  for (int j = 0; j < 4; j++) {
    v0[j] = fminf(p2v0 - 2.f * acc00[j], p2v1 - 2.f * acc01[j]);
    v1[j] = fminf(p2v0 - 2.f * acc10[j], p2v1 - 2.f * acc11[j]);
  }
#pragma unroll
  for (int mask = 1; mask < 16; mask <<= 1) {
#pragma unroll
    for (int j = 0; j < 4; j++) {
      v0[j] = fminf(v0[j], __shfl_xor(v0[j], mask));
      v1[j] = fminf(v1[j], __shfl_xor(v1[j], mask));
    }
  }
  if (lc == 0) {
#pragma unroll
    for (int j = 0; j < 4; j++) {
      red[lk * 4 + j][w] = v0[j];
      red[16 + lk * 4 + j][w] = v1[j];
    }
  }
  __syncthreads();
  if (t < 64) {
    float val = 0.f;
    if (t < nf) {
      float m = fminf(fminf(red[t][0], red[t][1]), fminf(red[t][2], red[t][3]));
      float d2 = f2s[t] + m;
      val = sqrtf(fmaxf(d2, 0.f)) * (1.0f / (float)N_FEAT);
    }
    val = wave_reduce_sum(val);
    if (t == 0) atomicAdd(out, val);
  }
}

extern "C" void kernel_launch(void* const* d_in, const int* in_sizes, int n_in,
                              void* d_out, int out_size, void* d_ws, size_t ws_size,
                              hipStream_t stream) {
  (void)in_sizes; (void)n_in; (void)out_size; (void)ws_size;
  const float* feat   = (const float*)d_in[0];
  const float* coarse = (const float*)d_in[1];
  const float* fine   = (const float*)d_in[2];
  float* out = (float*)d_out;

  int* assign = (int*)d_ws;                        // 8192 ints
  uch* histB  = (uch*)(assign + N_FEAT);           // 64 * 256 bytes, transposed

  k1_assign_kernel<<<K1BLK, 256, 0, stream>>>(feat, coarse, assign, histB, out);
  fine_mfma_kernel<<<MAXT2, 256, 0, stream>>>(feat, fine, assign, histB, out);
}